// Round 5
// baseline (84.945 us; speedup 1.0000x reference)
//
#include <hip/hip_runtime.h>

#define JOINTS 24
#define NG 2                         // 64-batch groups per wave
#define WAVES_PER_BLOCK 2
#define BLOCK_THREADS (WAVES_PER_BLOCK * 64)
#define NSTEP (3 * NG)

// Involution swizzle on 16B units within a 512-unit (8KiB) slice.
__device__ __forceinline__ int swz(int u) { return u ^ ((u >> 4) & 15); }

__device__ constexpr int kParents[JOINTS] = {-1, 0, 0, 0, 1, 2, 3, 4, 5, 6, 7, 8,
                                             9, 9, 9, 12, 13, 14, 16, 17, 18, 19, 20, 21};

template <int J>
__device__ __forceinline__ void do_joint(float (*pos)[3], const float4 qj,
                                         const float* __restrict__ skel) {
    constexpr int P = kParents[J];
    const float ox = skel[J * 3 + 0] - skel[P * 3 + 0];
    const float oy = skel[J * 3 + 1] - skel[P * 3 + 1];
    const float oz = skel[J * 3 + 2] - skel[P * 3 + 2];
    const float w = qj.x, x = qj.y, y = qj.z, z = qj.w;
    const float r00 = 1.f - 2.f * (y * y + z * z);
    const float r01 = 2.f * (x * y - z * w);
    const float r02 = 2.f * (x * z + y * w);
    const float r10 = 2.f * (x * y + z * w);
    const float r11 = 1.f - 2.f * (x * x + z * z);
    const float r12 = 2.f * (y * z - x * w);
    const float r20 = 2.f * (x * z - y * w);
    const float r21 = 2.f * (y * z + x * w);
    const float r22 = 1.f - 2.f * (x * x + y * y);
    pos[J][0] = pos[P][0] + r00 * ox + r01 * oy + r02 * oz;
    pos[J][1] = pos[P][1] + r10 * ox + r11 * oy + r12 * oz;
    pos[J][2] = pos[P][2] + r20 * ox + r21 * oy + r22 * oz;
}

template <int C>  // joints 8C .. 8C+7 from q[0..7]
__device__ __forceinline__ void compute_chunk(float (*pos)[3], const float4* q,
                                              const float* __restrict__ skel) {
    if constexpr (C == 0) {
        pos[0][0] = 0.f; pos[0][1] = 0.f; pos[0][2] = 0.f;
        do_joint<1>(pos, q[1], skel); do_joint<2>(pos, q[2], skel);
        do_joint<3>(pos, q[3], skel); do_joint<4>(pos, q[4], skel);
        do_joint<5>(pos, q[5], skel); do_joint<6>(pos, q[6], skel);
        do_joint<7>(pos, q[7], skel);
    } else if constexpr (C == 1) {
        do_joint<8>(pos, q[0], skel);  do_joint<9>(pos, q[1], skel);
        do_joint<10>(pos, q[2], skel); do_joint<11>(pos, q[3], skel);
        do_joint<12>(pos, q[4], skel); do_joint<13>(pos, q[5], skel);
        do_joint<14>(pos, q[6], skel); do_joint<15>(pos, q[7], skel);
    } else {
        do_joint<16>(pos, q[0], skel); do_joint<17>(pos, q[1], skel);
        do_joint<18>(pos, q[2], skel); do_joint<19>(pos, q[3], skel);
        do_joint<20>(pos, q[4], skel); do_joint<21>(pos, q[5], skel);
        do_joint<22>(pos, q[6], skel); do_joint<23>(pos, q[7], skel);
    }
}

// Issue 8 global_load_lds (width 16): 64 batches x 8 quats of chunk c -> slice.
__device__ __forceinline__ void issue_glds(const float4* __restrict__ rot4,
                                           float4* slice, int wb, int lane, int c) {
#pragma unroll
    for (int k = 0; k < 8; ++k) {
        const int u = k * 64 + lane;       // physical 16B unit this lane fills
        const int L = swz(u);              // logical element stored there
        const int row = L >> 3, col = L & 7;
        const float4* src = rot4 + ((size_t)(wb + row) * 24 + c * 8 + col);
        __builtin_amdgcn_global_load_lds(
            (const __attribute__((address_space(1))) void*)src,
            (__attribute__((address_space(3))) void*)(slice + k * 64),
            16, 0, 0);
    }
}

template <int W>
__device__ __forceinline__ void wait_vm() {
    if constexpr (W == 16)      asm volatile("s_waitcnt vmcnt(16)" ::: "memory");
    else if constexpr (W == 24) asm volatile("s_waitcnt vmcnt(24)" ::: "memory");
    else                        asm volatile("s_waitcnt vmcnt(32)" ::: "memory");
    __builtin_amdgcn_sched_barrier(0);
}

// Stage joints [8OC, 8OC+8) of 64 batches through `slice`, store coalesced.
template <int OC>
__device__ __forceinline__ void store_pass(const float (*pos)[3], float4* slice,
                                           float4* __restrict__ out4, int wb, int lane) {
#pragma unroll
    for (int i = 0; i < 6; ++i) {
        float v[4];
#pragma unroll
        for (int t = 0; t < 4; ++t) {
            const int f = i * 4 + t;                 // 0..23, compile-time
            v[t] = pos[OC * 8 + f / 3][f % 3];
        }
        slice[swz(lane * 8 + i)] = make_float4(v[0], v[1], v[2], v[3]);
    }
#pragma unroll
    for (int k = 0; k < 8; ++k) {
        const int u = k * 64 + lane;                 // linear -> coalesced
        const float4 vv = slice[swz(u)];
        const int row = u >> 3, col = u & 7;
        if (col < 6)
            out4[(size_t)(wb + row) * 18 + OC * 6 + col] = vv;
    }
}

// One pipeline step t: prefetch chunk t+2, counted-wait for chunk t, read+compute,
// then the pending store pass; end with lgkm drain so next step may glds this slice.
template <int t>
__device__ __forceinline__ void step(const float4* __restrict__ rot4,
                                     float4* S0, float4* S1, float4* S2,
                                     float4* __restrict__ out4, int wbase, int lane,
                                     float (*pos)[3], const float* __restrict__ skel) {
    constexpr int c = t % 3;
    constexpr int g = t / 3;
    constexpr int n = t + 2;                          // chunk to prefetch
    float4* const S[3] = {S0, S1, S2};
    if constexpr (n <= NSTEP - 1) {
        issue_glds(rot4, S[n % 3], wbase + (n / 3) * 64, lane, n % 3);
    }
    constexpr int last = NSTEP - 1;
    constexpr int W = (t <= 2) ? 16
                    : (t == last) ? 16
                    : (t == 3 || t == last - 1) ? 24 : 32;
    wait_vm<W>();

    float4 q[8];
#pragma unroll
    for (int j = 0; j < 8; ++j)
        q[j] = S[c][swz(lane * 8 + j)];               // compiler tracks lgkm deps
    compute_chunk<c>(pos, q, skel);

    if constexpr (c == 2)            store_pass<0>(pos, S[2], out4, wbase + g * 64, lane);
    if constexpr (c == 0 && t >= 3)  store_pass<1>(pos, S[0], out4, wbase + (g - 1) * 64, lane);
    if constexpr (c == 1 && t >= 4)  store_pass<2>(pos, S[1], out4, wbase + ((t - 4) / 3) * 64, lane);

    // All ds ops on this step's slices retired before the next step's glds reuse them.
    asm volatile("s_waitcnt lgkmcnt(0)" ::: "memory");
    __builtin_amdgcn_sched_barrier(0);
}

__global__ __launch_bounds__(BLOCK_THREADS) void fk_kernel(
    const float* __restrict__ rot,      // [B, 24, 4]
    const float* __restrict__ skel,     // [24, 3]
    float* __restrict__ out,            // [B, 24, 3]
    int nB)
{
    __shared__ float4 lds[WAVES_PER_BLOCK * 3 * 512];   // 48 KiB

    const int tid  = threadIdx.x;
    const int lane = tid & 63;
    const int wv   = tid >> 6;
    const int wbase = (blockIdx.x * WAVES_PER_BLOCK + wv) * (NG * 64);

    float4* S0 = &lds[wv * 3 * 512];
    float4* S1 = S0 + 512;
    float4* S2 = S0 + 1024;
    const float4* rot4 = reinterpret_cast<const float4*>(rot);
    float4* out4 = reinterpret_cast<float4*>(out);

    if (wbase + NG * 64 <= nB) {
        float pos[JOINTS][3];

        // Prologue: chunks 0,1 of group 0 in flight.
        issue_glds(rot4, S0, wbase, lane, 0);
        issue_glds(rot4, S1, wbase, lane, 1);

        step<0>(rot4, S0, S1, S2, out4, wbase, lane, pos, skel);
        step<1>(rot4, S0, S1, S2, out4, wbase, lane, pos, skel);
        step<2>(rot4, S0, S1, S2, out4, wbase, lane, pos, skel);
        step<3>(rot4, S0, S1, S2, out4, wbase, lane, pos, skel);
        step<4>(rot4, S0, S1, S2, out4, wbase, lane, pos, skel);
        step<5>(rot4, S0, S1, S2, out4, wbase, lane, pos, skel);

        // Tail: last group's remaining output passes.
        store_pass<1>(pos, S0, out4, wbase + (NG - 1) * 64, lane);
        store_pass<2>(pos, S1, out4, wbase + (NG - 1) * 64, lane);
    } else {
        // Partial range (unused at B=524288): direct per-lane path.
#pragma unroll
        for (int g = 0; g < NG; ++g) {
            const int b = wbase + g * 64 + lane;
            if (b >= nB) continue;
            const float4* q4 = rot4 + (size_t)b * 24;
            float pos[JOINTS][3];
            pos[0][0] = 0.f; pos[0][1] = 0.f; pos[0][2] = 0.f;
#pragma unroll
            for (int j = 1; j < JOINTS; ++j) {
                const int p = kParents[j];
                const float ox = skel[j * 3 + 0] - skel[p * 3 + 0];
                const float oy = skel[j * 3 + 1] - skel[p * 3 + 1];
                const float oz = skel[j * 3 + 2] - skel[p * 3 + 2];
                const float4 qj = q4[j];
                const float w = qj.x, x = qj.y, y = qj.z, z = qj.w;
                const float r00 = 1.f - 2.f * (y * y + z * z);
                const float r01 = 2.f * (x * y - z * w);
                const float r02 = 2.f * (x * z + y * w);
                const float r10 = 2.f * (x * y + z * w);
                const float r11 = 1.f - 2.f * (x * x + z * z);
                const float r12 = 2.f * (y * z - x * w);
                const float r20 = 2.f * (x * z - y * w);
                const float r21 = 2.f * (y * z + x * w);
                const float r22 = 1.f - 2.f * (x * x + y * y);
                pos[j][0] = pos[p][0] + r00 * ox + r01 * oy + r02 * oz;
                pos[j][1] = pos[p][1] + r10 * ox + r11 * oy + r12 * oz;
                pos[j][2] = pos[p][2] + r20 * ox + r21 * oy + r22 * oz;
            }
            float* o = out + (size_t)b * 72;
#pragma unroll
            for (int j = 0; j < JOINTS; ++j) {
                o[j * 3 + 0] = pos[j][0];
                o[j * 3 + 1] = pos[j][1];
                o[j * 3 + 2] = pos[j][2];
            }
        }
    }
}

extern "C" void kernel_launch(void* const* d_in, const int* in_sizes, int n_in,
                              void* d_out, int out_size, void* d_ws, size_t ws_size,
                              hipStream_t stream) {
    const float* rot  = (const float*)d_in[0];   // [B, 24, 4] f32
    const float* skel = (const float*)d_in[1];   // [24, 3] f32
    float* out = (float*)d_out;                  // [B, 24, 3] f32

    const int B = in_sizes[0] / (JOINTS * 4);    // 524288
    const int perBlock = BLOCK_THREADS / 64 * NG * 64;   // 256 batches/block
    const int grid = (B + perBlock - 1) / perBlock;      // 2048
    fk_kernel<<<grid, BLOCK_THREADS, 0, stream>>>(rot, skel, out, B);
}